// Round 4
// baseline (647.160 us; speedup 1.0000x reference)
//
#include <hip/hip_runtime.h>
#include <math.h>
#include <stdint.h>

// Bayesian DAG marginal propagation, N=4096, K=14 parents, C=2^14 configs.
//
// v4: dynamic work claiming on the PROVEN-resident 256-block config.
// v3's 512-block variant was not co-resident under cooperative launch
// (out stayed zero) -> never exceed 1 block/CU for spin-wait code.
//
// Convoy fix without more blocks: a global atomic counter hands out nodes
// in index (= topological) order. Any free block claims the lowest
// unclaimed node, so ready nodes are never stuck behind a block that is
// spinning on an unrelated late parent. Deadlock-free: nodes are claimed
// in increasing index, so the smallest incomplete node always has all
// parents complete -> its holder progresses -> induction.
//
// Math (verified absmax 0.0 in v2): linear-space bit-fold
//   S = sum_c sigma(x_c) * prod_k w_k(bit_k(c)),  w_k = (1-p_k, p_k)
// collapsed by 14 pairwise folds v' = fma(p, v1-v0, v0):
//   4 in-register levels (c bits 10..13 <-> parents 3..0)
//   6 shfl_xor levels    (c bits 0..5   <-> parents 13..8)
//   4 cross-wave levels  (c bits 6..9   <-> parents 7..4)
// Flag word IS the payload (marginal probability). Sentinel 0x7F7F7F7F.

#define NN     4096
#define KK     14
#define CC     16384
#define NROOTS 64
#define NBLK   256
#define NTHR   1024
#define PT     (CC / NTHR)   // 16 elements per thread
#define SENTIN 0x7F7F7F7Fu

__global__ __launch_bounds__(NTHR, 4) void bayes_dag_kernel(
    const float* __restrict__ logits,
    const int*   __restrict__ parents,
    float*       __restrict__ out,
    unsigned*    __restrict__ flagv,   // N words: float bits of marginal prob
    unsigned*    __restrict__ ctr)     // claim counter (0-based over non-roots)
{
    __shared__ float pvals[KK];        // clipped parent probabilities
    __shared__ float redLds[NTHR / 64];
    __shared__ int   ndLds;            // next claimed node

    const int tid  = threadIdx.x;
    const int lane = tid & 63;
    const int wv   = tid >> 6;
    const float LOG2E = 1.4426950408889634f;

    // roots: block b < 64 publishes root b
    if (blockIdx.x < NROOTS && tid == 0) {
        float x = logits[(size_t)blockIdx.x * CC];
        float p = __builtin_amdgcn_rcpf(1.f + exp2f(-x * LOG2E));
        __hip_atomic_exchange(&flagv[blockIdx.x], __float_as_uint(p),
                              __ATOMIC_RELAXED, __HIP_MEMORY_SCOPE_AGENT);
        out[blockIdx.x] = p;
    }

    // initial claim
    if (tid == 0) {
        unsigned c = __hip_atomic_fetch_add(ctr, 1u, __ATOMIC_RELAXED,
                                            __HIP_MEMORY_SCOPE_AGENT);
        ndLds = NROOTS + (int)c;
    }
    __syncthreads();
    int node = ndLds;

    // preload current row: c = m*NTHR + tid (fully coalesced)
    float xs[PT];
    {
        const float* row = logits + (size_t)(node < NN ? node : 0) * CC;
        #pragma unroll
        for (int m = 0; m < PT; ++m) xs[m] = row[m * NTHR + tid];
    }

    while (node < NN) {
        // ---- parent indices early (in flight before the spin) ----
        int pidx = 0;
        if (wv == 0 && lane < KK) pidx = parents[node * KK + lane];

        // ---- parent-independent: sigmoid of current row ----
        float sig[PT];
        #pragma unroll
        for (int m = 0; m < PT; ++m)
            sig[m] = __builtin_amdgcn_rcpf(1.f + exp2f(-xs[m] * LOG2E));

        // ---- wave 0: spin on parent flags ----
        if (wv == 0) {
            unsigned v = SENTIN;
            int guard = 0;
            for (;;) {
                if (lane < KK)
                    v = __hip_atomic_load(&flagv[pidx], __ATOMIC_RELAXED,
                                          __HIP_MEMORY_SCOPE_AGENT);
                if (__all(lane >= KK || v != SENTIN)) break;
                if (++guard > (1 << 22)) break;   // visible-failure escape
                __builtin_amdgcn_s_sleep(1);
            }
            if (lane < KK) {
                float pf = __uint_as_float(v);
                pvals[lane] = fminf(fmaxf(pf, 1e-6f), 1.f - 1e-6f);
            }
        }
        // claim the NEXT node now, so its row prefetch overlaps fold+publish
        if (tid == 0) {
            unsigned c = __hip_atomic_fetch_add(ctr, 1u, __ATOMIC_RELAXED,
                                                __HIP_MEMORY_SCOPE_AGENT);
            ndLds = NROOTS + (int)c;
        }
        __syncthreads();
        const int nxt = ndLds;

        // issue next row's loads (in flight during fold/publish/next spin)
        const float* nrow = logits + (size_t)(nxt < NN ? nxt : 0) * CC;
        float xn[PT];
        #pragma unroll
        for (int m = 0; m < PT; ++m) xn[m] = nrow[m * NTHR + tid];

        // broadcast parent probs to registers
        float pv[KK];
        #pragma unroll
        for (int k = 0; k < KK; ++k) pv[k] = pvals[k];

        // ---- 4 in-register fold levels: m bit j <-> c bit 10+j <-> parent 3-j ----
        float v8[8];
        #pragma unroll
        for (int j = 0; j < 8; ++j)
            v8[j] = fmaf(pv[3], sig[2*j+1] - sig[2*j], sig[2*j]);
        float v4[4];
        #pragma unroll
        for (int j = 0; j < 4; ++j)
            v4[j] = fmaf(pv[2], v8[2*j+1] - v8[2*j], v8[2*j]);
        float v2[2];
        #pragma unroll
        for (int j = 0; j < 2; ++j)
            v2[j] = fmaf(pv[1], v4[2*j+1] - v4[2*j], v4[2*j]);
        float acc = fmaf(pv[0], v2[1] - v2[0], v2[0]);

        // ---- 6 lane fold levels: lane bit t <-> c bit t <-> parent 13-t ----
        #pragma unroll
        for (int t = 0; t < 6; ++t) {
            float other = __shfl_xor(acc, 1 << t, 64);
            bool  bit   = (lane >> t) & 1;
            float a = bit ? other : acc;   // config bit = 0 value
            float b = bit ? acc : other;   // config bit = 1 value
            acc = fmaf(pv[13 - t], b - a, a);
        }
        if (lane == 0) redLds[wv] = acc;
        __syncthreads();

        // ---- 4 cross-wave fold levels: wv bit t <-> c bit 6+t <-> parent 7-t ----
        if (wv == 0) {
            float val = (lane < NTHR / 64) ? redLds[lane] : 0.f;
            #pragma unroll
            for (int t = 0; t < 4; ++t) {
                float other = __shfl_xor(val, 1 << t, 64);
                bool  bit   = (lane >> t) & 1;
                float a = bit ? other : val;
                float b = bit ? val : other;
                val = fmaf(pv[7 - t], b - a, a);
            }
            if (lane == 0) {
                // flag FIRST (children unblock), out second
                __hip_atomic_exchange(&flagv[node], __float_as_uint(val),
                                      __ATOMIC_RELAXED, __HIP_MEMORY_SCOPE_AGENT);
                out[node] = val;
            }
        }

        // rotate prefetch buffer
        #pragma unroll
        for (int m = 0; m < PT; ++m) xs[m] = xn[m];
        node = nxt;
    }
}

extern "C" void kernel_launch(void* const* d_in, const int* in_sizes, int n_in,
                              void* d_out, int out_size, void* d_ws, size_t ws_size,
                              hipStream_t stream) {
    const float* logits  = (const float*)d_in[0];
    // d_in[1] = configs — encoded analytically in the fold order, unused
    const int*   parents = (const int*)d_in[2];
    // d_in[3] = root_mask — node < 64, unused
    float*    out   = (float*)d_out;
    unsigned* flagv = (unsigned*)d_ws;        // N words
    unsigned* ctr   = flagv + NN;             // 1 word claim counter

    hipMemsetAsync(flagv, 0x7F, NN * sizeof(unsigned), stream);
    hipMemsetAsync(ctr, 0, sizeof(unsigned), stream);

    void* args[] = { (void*)&logits, (void*)&parents, (void*)&out,
                     (void*)&flagv, (void*)&ctr };
    hipLaunchCooperativeKernel((const void*)bayes_dag_kernel,
                               dim3(NBLK), dim3(NTHR), args, 0, stream);
}